// Round 1
// baseline (185.193 us; speedup 1.0000x reference)
//
#include <hip/hip_runtime.h>
#include <math.h>

#define LQ 2048
#define NH 8
#define DD 64
#define SK 80
#define UTOP 80
#define NB 2
#define CH 32        // number of key chunks per (b,h)
#define CK2 64       // keys per chunk (processed as 2 sub-chunks of 32)
#define CKS 32       // keys per sub-chunk

// ---------------- Kernel A: M[b,h,l] = max_s(dot) - sum_s(dot)/L ----------------
// wave = one (b,h,l); 4 groups of 16 lanes, each group does one sampled dot via float4.
__global__ __launch_bounds__(256) void kA_M(const float* __restrict__ Q,
                                            const float* __restrict__ K,
                                            const int* __restrict__ idxs,
                                            float* __restrict__ M) {
    int b    = blockIdx.x & 1;                       // pin batch per XCD (round-robin %8)
    int rid  = ((blockIdx.x >> 1) << 2) + (threadIdx.x >> 6);   // 0..16383
    int lane = threadIdx.x & 63;
    int h = rid >> 11;
    int l = rid & 2047;
    int g = lane >> 4;
    int t = lane & 15;
    const float4* Qrow = (const float4*)(Q + (((size_t)(b * LQ + l) * NH + h) << 6));
    float4 q4 = Qrow[t];
    float maxv = -INFINITY, sumv = 0.f;
    const int* idxrow = idxs + l * SK;
#pragma unroll
    for (int it = 0; it < SK / 4; ++it) {
        int s = (it << 2) + g;
        int kidx = idxrow[s];
        const float4* Krow = (const float4*)(K + (((size_t)(b * LQ + kidx) * NH + h) << 6));
        float4 k4 = Krow[t];
        float p = q4.x * k4.x + q4.y * k4.y + q4.z * k4.z + q4.w * k4.w;
        p += __shfl_xor(p, 1, 16);
        p += __shfl_xor(p, 2, 16);
        p += __shfl_xor(p, 4, 16);
        p += __shfl_xor(p, 8, 16);
        maxv = fmaxf(maxv, p);
        sumv += p;
    }
    // combine across the 4 groups (each lane in a group holds identical values)
    maxv = fmaxf(maxv, __shfl_xor(maxv, 16));
    maxv = fmaxf(maxv, __shfl_xor(maxv, 32));
    sumv += __shfl_xor(sumv, 16);
    sumv += __shfl_xor(sumv, 32);
    if (lane == 0) M[(b * NH + h) * LQ + l] = maxv - sumv * (1.f / 2048.f);
}

// ---------------- Kernel B: top-80 per (b,h), descending, tie -> lower index ----------------
__global__ __launch_bounds__(256) void kB_topk(const float* __restrict__ M,
                                               int* __restrict__ Mtop) {
    int bh = blockIdx.x;  // 0..15 == b*8+h
    __shared__ float vals[LQ];
    __shared__ unsigned long long red[4];
    const float* Mrow = M + bh * LQ;
    for (int i = threadIdx.x; i < LQ; i += 256) vals[i] = Mrow[i];
    __syncthreads();
    for (int u = 0; u < UTOP; ++u) {
        unsigned long long best = 0ull;
#pragma unroll
        for (int i = 0; i < LQ / 256; ++i) {
            int e = i * 256 + threadIdx.x;   // stride-1 across lanes: conflict-free
            unsigned int bits = __float_as_uint(vals[e]);
            unsigned int mask = (unsigned int)(((int)bits >> 31)) | 0x80000000u;
            bits ^= mask;                    // monotonic: larger uint == larger float
            unsigned long long key = ((unsigned long long)bits << 32) | (unsigned int)(2047 - e);
            if (key > best) best = key;
        }
#pragma unroll
        for (int off = 1; off < 64; off <<= 1) {
            unsigned long long o = __shfl_xor(best, off);
            if (o > best) best = o;
        }
        if ((threadIdx.x & 63) == 0) red[threadIdx.x >> 6] = best;
        __syncthreads();
        if (threadIdx.x == 0) {
            unsigned long long b0 = red[0] > red[1] ? red[0] : red[1];
            unsigned long long b1 = red[2] > red[3] ? red[2] : red[3];
            unsigned long long bb = b0 > b1 ? b0 : b1;
            int e = 2047 - (int)(bb & 0xffffffffu);
            Mtop[bh * UTOP + u] = e;
            vals[e] = -INFINITY;
        }
        __syncthreads();
    }
}

// ---------------- Kernel C: V_sum[b,h,d] (mean applied at use) ----------------
__global__ __launch_bounds__(256) void kC_vsum(const float* __restrict__ V,
                                               float* __restrict__ Vsum) {
    int bh = blockIdx.x & 15;
    int b = bh & 1, h = bh >> 1;
    int lc = blockIdx.x >> 4;        // 16 chunks of 128 l
    int d = threadIdx.x & 63;
    int lsub = threadIdx.x >> 6;
    float s = 0.f;
#pragma unroll 4
    for (int i = 0; i < 32; ++i) {
        int l = lc * 128 + lsub + (i << 2);
        s += V[(((size_t)(b * LQ + l) * NH + h) << 6) + d];
    }
    __shared__ float sc[256];
    sc[threadIdx.x] = s;
    __syncthreads();
    if (threadIdx.x < 64) {
        float tot = sc[threadIdx.x] + sc[threadIdx.x + 64] + sc[threadIdx.x + 128] + sc[threadIdx.x + 192];
        atomicAdd(&Vsum[(b * NH + h) * DD + d], tot);
    }
}

// ---------------- Kernel D: flash partials over 64-key chunks (2x32 sub-chunks) ----------------
__global__ __launch_bounds__(256) void kD_attn(const float* __restrict__ Q,
                                               const float* __restrict__ K,
                                               const float* __restrict__ V,
                                               const int* __restrict__ Mtop,
                                               float* __restrict__ part_m,
                                               float* __restrict__ part_l,
                                               float* __restrict__ part_acc) {
    int code = blockIdx.x & 15;
    int b = code & 1, h = code >> 1;
    int bhl = b * NH + h;
    int c = blockIdx.x >> 4;                  // 0..31
    __shared__ int topl[UTOP];
    __shared__ __align__(16) float Qs[UTOP][68];
    __shared__ __align__(16) float Ks[CKS][68];
    __shared__ __align__(16) float Vs[CKS][68];
    __shared__ float Ps[UTOP][33];
    int tid = threadIdx.x;
    if (tid < UTOP) topl[tid] = Mtop[bhl * UTOP + tid];
    __syncthreads();
    // load Q_reduce: 80 rows x 16 float4
    for (int f = tid; f < UTOP * 16; f += 256) {
        int u = f >> 4, t4 = f & 15;
        const float4* src = (const float4*)(Q + (((size_t)(b * LQ + topl[u]) * NH + h) << 6));
        *((float4*)&Qs[u][t4 << 2]) = src[t4];
    }
    int i = tid >> 4, j = tid & 15;
    const float scale = 0.125f;
    float4 acc[5];
    float m_run[5], l_run[5];
#pragma unroll
    for (int n = 0; n < 5; ++n) {
        acc[n] = make_float4(0.f, 0.f, 0.f, 0.f);
        m_run[n] = -INFINITY;
        l_run[n] = 0.f;
    }
    for (int sc = 0; sc < 2; ++sc) {
        __syncthreads();  // Qs visible (sc=0) / previous PV done (sc=1)
        int kbase = c * CK2 + sc * CKS;
        for (int f = tid; f < CKS * 16; f += 256) {
            int k = f >> 4, t4 = f & 15;
            const float4* srck = (const float4*)(K + (((size_t)(b * LQ + kbase + k) * NH + h) << 6));
            *((float4*)&Ks[k][t4 << 2]) = srck[t4];
            const float4* srcv = (const float4*)(V + (((size_t)(b * LQ + kbase + k) * NH + h) << 6));
            *((float4*)&Vs[k][t4 << 2]) = srcv[t4];
        }
        __syncthreads();
        // scores: u = i*5+n, k in {j, j+16}
        float s0[5], s1[5];
#pragma unroll
        for (int n = 0; n < 5; ++n) { s0[n] = 0.f; s1[n] = 0.f; }
#pragma unroll
        for (int d4 = 0; d4 < 16; ++d4) {
            float4 ka = *((float4*)&Ks[j][d4 << 2]);
            float4 kb = *((float4*)&Ks[j + 16][d4 << 2]);
#pragma unroll
            for (int n = 0; n < 5; ++n) {
                float4 q4 = *((float4*)&Qs[i * 5 + n][d4 << 2]);
                s0[n] += q4.x * ka.x + q4.y * ka.y + q4.z * ka.z + q4.w * ka.w;
                s1[n] += q4.x * kb.x + q4.y * kb.y + q4.z * kb.z + q4.w * kb.w;
            }
        }
        float m32[5], l32[5];
#pragma unroll
        for (int n = 0; n < 5; ++n) {
            float a = s0[n] * scale, bb = s1[n] * scale;
            float m = fmaxf(a, bb);
#pragma unroll
            for (int off = 1; off < 16; off <<= 1) m = fmaxf(m, __shfl_xor(m, off, 16));
            float p0 = __expf(a - m), p1 = __expf(bb - m);
            float ls = p0 + p1;
#pragma unroll
            for (int off = 1; off < 16; off <<= 1) ls += __shfl_xor(ls, off, 16);
            int u = i * 5 + n;
            Ps[u][j] = p0;
            Ps[u][j + 16] = p1;
            m32[n] = m;
            l32[n] = ls;
        }
        __syncthreads();  // Ps visible
        // PV + online merge
#pragma unroll
        for (int n = 0; n < 5; ++n) {
            float4 pv = make_float4(0.f, 0.f, 0.f, 0.f);
            int u = i * 5 + n;
            for (int k = 0; k < CKS; ++k) {
                float4 v4 = *((float4*)&Vs[k][j << 2]);
                float p = Ps[u][k];
                pv.x += p * v4.x; pv.y += p * v4.y; pv.z += p * v4.z; pv.w += p * v4.w;
            }
            float m_new = fmaxf(m_run[n], m32[n]);
            float fo = __expf(m_run[n] - m_new);
            float fn = __expf(m32[n] - m_new);
            l_run[n] = l_run[n] * fo + l32[n] * fn;
            acc[n].x = acc[n].x * fo + fn * pv.x;
            acc[n].y = acc[n].y * fo + fn * pv.y;
            acc[n].z = acc[n].z * fo + fn * pv.z;
            acc[n].w = acc[n].w * fo + fn * pv.w;
            m_run[n] = m_new;
        }
    }
#pragma unroll
    for (int n = 0; n < 5; ++n) {
        int u = i * 5 + n;
        size_t base = ((size_t)(bhl * CH + c) * UTOP + u);
        if (j == 0) {
            part_m[base] = m_run[n];
            part_l[base] = l_run[n];
        }
        *((float4*)&part_acc[base * DD + (j << 2)]) = acc[n];
    }
}

// ---------------- Kernel E: combine chunk partials -> upd rows ----------------
__global__ __launch_bounds__(64) void kE_combine(const float* __restrict__ part_m,
                                                 const float* __restrict__ part_l,
                                                 const float* __restrict__ part_acc,
                                                 float* __restrict__ upd) {
    int bhl = blockIdx.x & 15;
    int u = blockIdx.x >> 4;
    int lane = threadIdx.x;
    float mc = -INFINITY, lc = 0.f;
    if (lane < CH) {
        mc = part_m[(size_t)(bhl * CH + lane) * UTOP + u];
        lc = part_l[(size_t)(bhl * CH + lane) * UTOP + u];
    }
    float m = mc;
#pragma unroll
    for (int off = 1; off < 64; off <<= 1) m = fmaxf(m, __shfl_xor(m, off));
    float alpha = __expf(mc - m);          // 0 for inactive lanes
    float lsum = lc * alpha;
#pragma unroll
    for (int off = 1; off < 64; off <<= 1) lsum += __shfl_xor(lsum, off);
    float accd = 0.f;
    for (int c = 0; c < CH; ++c) {
        float a = __shfl(alpha, c);
        accd += a * part_acc[((size_t)(bhl * CH + c) * UTOP + u) * DD + lane];
    }
    upd[(size_t)(bhl * UTOP + u) * DD + lane] = accd / lsum;
}

// ---------------- Kernel F: winner scatter (np last-wins) + V_mean fill + transpose ----------------
__global__ __launch_bounds__(256) void kF_write(const int* __restrict__ Mtop,
                                                const float* __restrict__ upd,
                                                const float* __restrict__ Vsum,
                                                float* __restrict__ out) {
    int bhl = blockIdx.x;            // 0..15 == b*8+h
    int b = bhl >> 3, h = bhl & 7;
    __shared__ int topl[UTOP];
    __shared__ int winner[UTOP];
    int tid = threadIdx.x;
    if (tid < UTOP) {
        topl[tid] = Mtop[bhl * UTOP + tid];
        winner[tid] = -1;
    }
    __syncthreads();
    if (tid == 0) {
        for (int u = 0; u < UTOP; ++u) {
            int r = topl[u];
            if (r > UTOP - 1) r = UTOP - 1;   // clip(M_top, 0, 79)
            winner[r] = u;                    // last-wins, u ascending
        }
    }
    __syncthreads();
    for (int f = tid; f < UTOP * DD; f += 256) {
        int r = f >> 6, d = f & 63;
        int w = winner[r];
        float val = (w >= 0) ? upd[(size_t)(bhl * UTOP + w) * DD + d]
                             : Vsum[bhl * DD + d] * (1.f / 2048.f);
        out[(((size_t)(b * UTOP + r)) * NH + h) * DD + d] = val;
    }
}

extern "C" void kernel_launch(void* const* d_in, const int* in_sizes, int n_in,
                              void* d_out, int out_size, void* d_ws, size_t ws_size,
                              hipStream_t stream) {
    const float* Q = (const float*)d_in[0];
    const float* K = (const float*)d_in[1];
    const float* V = (const float*)d_in[2];
    const int* idxs = (const int*)d_in[3];
    float* out = (float*)d_out;

    char* base = (char*)d_ws;
    float* M        = (float*)(base + 0);          // 32768 f  -> 131072 B
    int*   Mtop     = (int*)  (base + 131072);     // 1280 i   -> 5120 B
    float* Vsum     = (float*)(base + 136192);     // 1024 f   -> 4096 B
    float* part_m   = (float*)(base + 140288);     // 16*32*80 -> 163840 B
    float* part_l   = (float*)(base + 304128);     // 163840 B
    float* part_acc = (float*)(base + 467968);     // 16*32*80*64 f -> 10485760 B
    float* upd      = (float*)(base + 10953728);   // 16*80*64 f -> 327680 B
    // total 11281408 B

    hipMemsetAsync(Vsum, 0, NB * NH * DD * sizeof(float), stream);

    kA_M   <<<8192, 256, 0, stream>>>(Q, K, idxs, M);
    kB_topk<<<16,   256, 0, stream>>>(M, Mtop);
    kC_vsum<<<256,  256, 0, stream>>>(V, Vsum);
    kD_attn<<<16 * CH, 256, 0, stream>>>(Q, K, V, Mtop, part_m, part_l, part_acc);
    kE_combine<<<16 * UTOP, 64, 0, stream>>>(part_m, part_l, part_acc, upd);
    kF_write<<<16, 256, 0, stream>>>(Mtop, upd, Vsum, out);
}